// Round 5
// baseline (177.367 us; speedup 1.0000x reference)
//
#include <hip/hip_runtime.h>

#define B_  256
#define T_  256
#define S_  20
#define U1  32
#define G1  128   // 4*U1
#define U2  24
#define G2  96    // 4*U2
#define NT  16    // 16-row t-tiles per sequence

typedef __attribute__((ext_vector_type(8))) short short8;   // 8 bf16 = 4 VGPRs
typedef __attribute__((ext_vector_type(4))) float f32x4;    // MFMA acc
typedef __attribute__((ext_vector_type(2))) float f32x2;    // pk pair

#define KSIG  (-1.44269504f)   // -log2(e)
#define KTANH ( 2.88539008f)   // 2*log2(e)

// Raw-HW activations (v_exp_f32 = 2^x, pre-scaled by log2e). R7: 134->74us.
__device__ __forceinline__ float sigmoidf_(float x) {
    return __builtin_amdgcn_rcpf(1.0f + __builtin_amdgcn_exp2f(x * KSIG));
}
__device__ __forceinline__ float tanhf_fast(float x) {   // 1 - 2/(1+e^{2x})
    return 1.0f - 2.0f * __builtin_amdgcn_rcpf(1.0f + __builtin_amdgcn_exp2f(x * KTANH));
}
// quad_perm [1,0,3,2]: lane ^= 1 swap, pure-VALU
__device__ __forceinline__ float dpp_xor1(float x) {
    return __int_as_float(__builtin_amdgcn_update_dpp(
        0, __float_as_int(x), 0xB1, 0xF, 0xF, true));
}
// d = 1 + exp2(k*z), componentwise exp2 (trans is scalar-only; mul/add pack)
__device__ __forceinline__ f32x2 dexp2(f32x2 z, float k) {
    f32x2 t = z * k;
    f32x2 e;
    e.x = __builtin_amdgcn_exp2f(t.x);
    e.y = __builtin_amdgcn_exp2f(t.y);
    return e + 1.0f;
}
// elementwise recip of 4 independent denoms with 2 rcp + 3 pk_mul (vs 4 rcp)
__device__ __forceinline__ void brcp4(f32x2 d01, f32x2 d23, f32x2& s01, f32x2& s23) {
    const f32x2 m = d01 * d23;
    f32x2 R;
    R.x = __builtin_amdgcn_rcpf(m.x);
    R.y = __builtin_amdgcn_rcpf(m.y);
    s01 = R * d23;
    s23 = R * d01;
}

__device__ __forceinline__ unsigned short f2bf(float a) {
    unsigned int u = __float_as_uint(a);
    u += 0x7FFFu + ((u >> 16) & 1u);
    return (unsigned short)(u >> 16);
}
__device__ __forceinline__ unsigned int pack2bf(float a, float b) {
    unsigned int ua = __float_as_uint(a); ua += 0x7FFFu + ((ua >> 16) & 1u);
    unsigned int ub = __float_as_uint(b); ub += 0x7FFFu + ((ub >> 16) & 1u);
    return (ua >> 16) | (ub & 0xFFFF0000u);
}
union frag_u { short8 v; unsigned int u[4]; };
union h2x  { unsigned int u32; _Float16 h[2]; };

// =====================================================================
// R17 SPLIT PATH (used when ws_size fits P = 12.6 MB):
//   prod_kernel: 4096 blocks x 1 wave, one inner-LSTM tile each -> gP.
//     Machine-wide parallelism for the trans-bound phase-1 work; tiles
//     beyond len skipped (~half the work for avg len=128).
//   cons_kernel: 256 blocks x 1 wave, phase-2 only. P tiles prefetched
//     from global into double-buffered registers (latency hidden under
//     16-step windows). No flags/spins; stream order synchronizes.
// Fallback: the proven R4 fused kernel, byte-identical behavior.
// =====================================================================

__global__ __attribute__((amdgpu_flat_work_group_size(64, 64)))
void prod_kernel(
    const float* __restrict__ x,        // [B*T*S]
    const int*   __restrict__ lengths,  // [B]
    const float* __restrict__ Wi,       // [G1]
    const float* __restrict__ Ui,       // [U1*G1]
    const float* __restrict__ bi,       // [G1]
    const float* __restrict__ Wo,       // [U1*G2]
    const float* __restrict__ bo,       // [G2]
    _Float16*    __restrict__ gP)       // [B][T][G2] unit-major pair layout
{
    __shared__ __align__(16) unsigned short hbb[16][40];
    const int blk  = blockIdx.x;
    const int b    = blk >> 4;
    const int tile = blk & 15;
    const int len  = lengths[b];
    const int wt0  = tile * 16;
    if (wt0 >= len) return;              // rows >= len never read by consumer
    const int lane = threadIdx.x & 63;
    const int q    = lane >> 4;
    const int n    = lane & 15;

    frag_u Bui[8];
#pragma unroll
    for (int tt = 0; tt < 8; ++tt)
#pragma unroll
        for (int k2 = 0; k2 < 4; ++k2)
            Bui[tt].u[k2] = pack2bf(Ui[(8 * q + 2 * k2) * G1 + 16 * tt + n],
                                    Ui[(8 * q + 2 * k2 + 1) * G1 + 16 * tt + n]);
    frag_u Bwo[6];
#pragma unroll
    for (int tt = 0; tt < 6; ++tt)
#pragma unroll
        for (int k2 = 0; k2 < 4; ++k2)
            Bwo[tt].u[k2] = pack2bf(Wo[(8 * q + 2 * k2) * G2 + 16 * tt + n],
                                    Wo[(8 * q + 2 * k2 + 1) * G2 + 16 * tt + n]);
    float bi_l[8], Wi_l[8], bo_l[6];
#pragma unroll
    for (int tt = 0; tt < 8; ++tt) { bi_l[tt] = bi[16 * tt + n]; Wi_l[tt] = Wi[16 * tt + n]; }
#pragma unroll
    for (int tt = 0; tt < 6; ++tt) bo_l[tt] = bo[16 * tt + n];
    int pcol[6];
#pragma unroll
    for (int tt = 0; tt < 6; ++tt) {
        const int col = 16 * tt + n;
        const int g = col / 24;
        pcol[tt] = (col - 24 * g) * 4 + g;
    }

    const float* xr = x + (size_t)(b * T_ + wt0 + 4 * q) * S_;
    f32x2 c01[2], c23[2];
#pragma unroll
    for (int uh = 0; uh < 2; ++uh) { c01[uh] = {0.0f, 0.0f}; c23[uh] = {0.0f, 0.0f}; }

    auto activate = [&](f32x4* acc) {
#pragma unroll
        for (int uh = 0; uh < 2; ++uh) {
            const f32x2 zi01 = { acc[0 + uh][0], acc[0 + uh][1] };
            const f32x2 zi23 = { acc[0 + uh][2], acc[0 + uh][3] };
            const f32x2 zf01 = { acc[2 + uh][0], acc[2 + uh][1] };
            const f32x2 zf23 = { acc[2 + uh][2], acc[2 + uh][3] };
            const f32x2 zg01 = { acc[4 + uh][0], acc[4 + uh][1] };
            const f32x2 zg23 = { acc[4 + uh][2], acc[4 + uh][3] };
            const f32x2 zo01 = { acc[6 + uh][0], acc[6 + uh][1] };
            const f32x2 zo23 = { acc[6 + uh][2], acc[6 + uh][3] };

            f32x2 si01, si23, sf01, sf23, rg01, rg23, so01, so23;
            brcp4(dexp2(zi01, KSIG),  dexp2(zi23, KSIG),  si01, si23);
            brcp4(dexp2(zf01, KSIG),  dexp2(zf23, KSIG),  sf01, sf23);
            brcp4(dexp2(zg01, KTANH), dexp2(zg23, KTANH), rg01, rg23);
            brcp4(dexp2(zo01, KSIG),  dexp2(zo23, KSIG),  so01, so23);
            const f32x2 g01 = 1.0f - 2.0f * rg01;
            const f32x2 g23 = 1.0f - 2.0f * rg23;
            c01[uh] = sf01 * c01[uh] + si01 * g01;
            c23[uh] = sf23 * c23[uh] + si23 * g23;
            f32x2 rc01, rc23;
            brcp4(dexp2(c01[uh], KTANH), dexp2(c23[uh], KTANH), rc01, rc23);
            const f32x2 t01 = 1.0f - 2.0f * rc01;
            const f32x2 t23 = 1.0f - 2.0f * rc23;
            const f32x2 h01 = so01 * t01;
            const f32x2 h23 = so23 * t23;
            hbb[4 * q + 0][n + 16 * uh] = f2bf(h01.x);
            hbb[4 * q + 1][n + 16 * uh] = f2bf(h01.y);
            hbb[4 * q + 2][n + 16 * uh] = f2bf(h23.x);
            hbb[4 * q + 3][n + 16 * uh] = f2bf(h23.y);
        }
    };

    float xc[4];
#pragma unroll
    for (int r = 0; r < 4; ++r) xc[r] = xr[r * S_];

    // peeled s = 0 (h == 0: no MFMA)
    {
        const f32x2 xc01 = { xc[0], xc[1] }, xc23 = { xc[2], xc[3] };
        f32x4 acc[8];
#pragma unroll
        for (int tt = 0; tt < 8; ++tt) {
            const f32x2 a01 = xc01 * Wi_l[tt] + bi_l[tt];
            const f32x2 a23 = xc23 * Wi_l[tt] + bi_l[tt];
            acc[tt][0] = a01.x; acc[tt][1] = a01.y;
            acc[tt][2] = a23.x; acc[tt][3] = a23.y;
        }
        activate(acc);
    }
#pragma unroll
    for (int r = 0; r < 4; ++r) xc[r] = xr[r * S_ + 1];

#pragma unroll 1
    for (int s = 1; s < S_; ++s) {
        const int sn = (s + 1 < S_) ? s + 1 : S_ - 1;
        float xnx[4];
#pragma unroll
        for (int r = 0; r < 4; ++r) xnx[r] = xr[r * S_ + sn];

        const f32x2 xc01 = { xc[0], xc[1] }, xc23 = { xc[2], xc[3] };
        f32x4 acc[8];
#pragma unroll
        for (int tt = 0; tt < 8; ++tt) {
            const f32x2 a01 = xc01 * Wi_l[tt] + bi_l[tt];
            const f32x2 a23 = xc23 * Wi_l[tt] + bi_l[tt];
            acc[tt][0] = a01.x; acc[tt][1] = a01.y;
            acc[tt][2] = a23.x; acc[tt][3] = a23.y;
        }

        const short8 A = *(const short8*)&hbb[n][8 * q];
#pragma unroll
        for (int tt = 0; tt < 8; ++tt)
            acc[tt] = __builtin_amdgcn_mfma_f32_16x16x32_bf16(A, Bui[tt].v, acc[tt], 0, 0, 0);

        activate(acc);
#pragma unroll
        for (int r = 0; r < 4; ++r) xc[r] = xnx[r];
    }

    // P tile = bo + h @ Wo -> global, unit-major pair layout
    {
        const short8 A = *(const short8*)&hbb[n][8 * q];
        f32x4 accp[6];
#pragma unroll
        for (int tt = 0; tt < 6; ++tt) {
#pragma unroll
            for (int r = 0; r < 4; ++r) accp[tt][r] = bo_l[tt];
            accp[tt] = __builtin_amdgcn_mfma_f32_16x16x32_bf16(A, Bwo[tt].v, accp[tt], 0, 0, 0);
        }
#pragma unroll
        for (int r = 0; r < 4; ++r) {
            const size_t tr = (size_t)(b * T_ + wt0 + 4 * q + r) * G2;
#pragma unroll
            for (int tt = 0; tt < 6; ++tt)
                gP[tr + pcol[tt]] = (_Float16)accp[tt][r];
        }
    }
}

__global__ __attribute__((amdgpu_flat_work_group_size(64, 64)))
void cons_kernel(
    const int*      __restrict__ lengths,  // [B]
    const float*    __restrict__ Uo,       // [U2*G2]
    const float*    __restrict__ Wd,       // [U2]
    const float*    __restrict__ bd,       // [1]
    const _Float16* __restrict__ gP,       // [B][T][G2]
    float*          __restrict__ out)      // [B]
{
    const int b    = blockIdx.x;
    const int len  = lengths[b];             // >= 1
    const int lane = threadIdx.x & 63;
    // Parity pipeline (R4): even lane 2u holds (z_i,z_f) prescaled KSIG; odd
    // (z_g,z_o) prescaled (KTANH,KSIG). cs = KTANH*c and hu live on EVEN.
    const int p = lane & 1;
    const int u = (lane < 2 * U2) ? (lane >> 1) : (U2 - 1);
    const int cA = p ? (2 * U2 + u) : u;
    const int cB = p ? (3 * U2 + u) : (U2 + u);

    const float kx = p ? KTANH : KSIG;
    const f32x2 kv  = { kx, KSIG };
    const f32x2 mAB = { p ? (-2.0f * KTANH) : 1.0f, 1.0f };
    const f32x2 aAB = { p ? KTANH : 0.0f, 0.0f };

    f32x2 w2_[U2];                           // prescaled weight pairs
#pragma unroll
    for (int k = 0; k < U2; ++k) {
        w2_[k].x = Uo[k * G2 + cA] * kx;
        w2_[k].y = Uo[k * G2 + cB] * KSIG;
    }

    const int rowoff = 8 * u + 4 * p;        // bytes within a 192 B row
    const char* Pb = (const char*)gP + (size_t)b * T_ * G2 * 2;
    const int nfull  = len >> 4;
    const int rem    = len & 15;
    const int ntiles = (len + 15) >> 4;

    unsigned bufA[16], bufB[16];
    float cs = 0.0f, hu = 0.0f;

#define LROW(T) (*reinterpret_cast<const unsigned*>(Pb + (size_t)(T) * (G2 * 2) + rowoff))

// one recurrence step; hu fma-merged: hu = fma(-2*swy, r2, swy)
#define STEPC(RW) do {                                                        \
    h2x s_; s_.u32 = (RW);                                                    \
    f32x2 pr; pr.x = (float)s_.h[0]; pr.y = (float)s_.h[1]; pr *= kv;         \
    float hk[U2];                                                             \
    _Pragma("unroll")                                                         \
    for (int kq = 0; kq < U2; ++kq)                                           \
        hk[kq] = __int_as_float(                                              \
            __builtin_amdgcn_readlane(__float_as_int(hu), 2 * kq));           \
    f32x2 ab0 = pr;                                                           \
    f32x2 ab1 = {0.f,0.f}, ab2 = {0.f,0.f}, ab3 = {0.f,0.f};                  \
    f32x2 ab4 = {0.f,0.f}, ab5 = {0.f,0.f}, ab6 = {0.f,0.f}, ab7 = {0.f,0.f}; \
    _Pragma("unroll")                                                         \
    for (int mq = 0; mq < 3; ++mq) {                                          \
        ab0 += w2_[8 * mq + 0] * hk[8 * mq + 0];                              \
        ab1 += w2_[8 * mq + 1] * hk[8 * mq + 1];                              \
        ab2 += w2_[8 * mq + 2] * hk[8 * mq + 2];                              \
        ab3 += w2_[8 * mq + 3] * hk[8 * mq + 3];                              \
        ab4 += w2_[8 * mq + 4] * hk[8 * mq + 4];                              \
        ab5 += w2_[8 * mq + 5] * hk[8 * mq + 5];                              \
        ab6 += w2_[8 * mq + 6] * hk[8 * mq + 6];                              \
        ab7 += w2_[8 * mq + 7] * hk[8 * mq + 7];                              \
    }                                                                         \
    const f32x2 zz = (((ab0 + ab1) + (ab2 + ab3)) +                           \
                      ((ab4 + ab5) + (ab6 + ab7)));                           \
    f32x2 e_;                                                                 \
    e_.x = __builtin_amdgcn_exp2f(zz.x);                                      \
    e_.y = __builtin_amdgcn_exp2f(zz.y);                                      \
    const f32x2 d_ = e_ + 1.0f;                                               \
    f32x2 r_;                                                                 \
    r_.x = __builtin_amdgcn_rcpf(d_.x);                                       \
    r_.y = __builtin_amdgcn_rcpf(d_.y);                                       \
    const f32x2 o2 = r_ * mAB + aAB;                                          \
    const float swx  = dpp_xor1(o2.x);                                        \
    const float swy  = dpp_xor1(o2.y);                                        \
    const float swy2 = -2.0f * swy;          /* exact; off the cs-chain */    \
    cs = o2.y * cs + o2.x * swx;                                              \
    const float e2 = __builtin_amdgcn_exp2f(cs);                              \
    const float r2 = __builtin_amdgcn_rcpf(1.0f + e2);                        \
    hu = swy2 * r2 + swy;                                                     \
} while (0)

// full 16-step tile, NO per-step guards; next tile's 16 loads issued
// mid-tile (vmcnt wait lands at next tile's first use -> latency hidden)
#define FULLT(K, CUR, NXT, J0) do {                                           \
    _Pragma("unroll")                                                         \
    for (int j = (J0); j < 8; ++j) STEPC(CUR[j]);                             \
    if ((K) + 1 < ntiles) {                                                   \
        _Pragma("unroll")                                                     \
        for (int j = 0; j < 16; ++j) NXT[j] = LROW(16 * ((K) + 1) + j);       \
    }                                                                         \
    _Pragma("unroll")                                                         \
    for (int j = 8; j < 16; ++j) STEPC(CUR[j]);                               \
} while (0)

#define TAILT(K, CUR, J0) do {                                                \
    _Pragma("unroll")                                                         \
    for (int j = (J0); j < 16; ++j) {                                         \
        if (16 * (K) + j >= len) break;                                       \
        STEPC(CUR[j]);                                                        \
    }                                                                         \
} while (0)

#pragma unroll
    for (int j = 0; j < 16; ++j) bufA[j] = LROW(j);

    {   // peeled t = 0 (h == 0, c == 0)
        h2x s_; s_.u32 = bufA[0];
        f32x2 z0; z0.x = (float)s_.h[0]; z0.y = (float)s_.h[1]; z0 *= kv;
        f32x2 e_;
        e_.x = __builtin_amdgcn_exp2f(z0.x);
        e_.y = __builtin_amdgcn_exp2f(z0.y);
        const f32x2 d_ = e_ + 1.0f;
        f32x2 r_;
        r_.x = __builtin_amdgcn_rcpf(d_.x);
        r_.y = __builtin_amdgcn_rcpf(d_.y);
        const f32x2 o2 = r_ * mAB + aAB;
        const float swx = dpp_xor1(o2.x);
        const float swy = dpp_xor1(o2.y);
        cs = o2.x * swx;                     // c_prev = 0
        const float e2 = __builtin_amdgcn_exp2f(cs);
        const float r2 = __builtin_amdgcn_rcpf(1.0f + e2);
        hu = (-2.0f * swy) * r2 + swy;
    }

    if (ntiles == 1) {
        TAILT(0, bufA, 1);
    } else {
        FULLT(0, bufA, bufB, 1);
#pragma unroll 1
        for (int k = 1; k < nfull; ++k) {
            if (k & 1) FULLT(k, bufB, bufA, 0);
            else       FULLT(k, bufA, bufB, 0);
        }
        if (rem) {
            if (nfull & 1) TAILT(nfull, bufB, 0);
            else           TAILT(nfull, bufA, 0);
        }
    }

    // dense sigmoid head (h on even lanes)
    float acc = bd[0];
#pragma unroll
    for (int k = 0; k < U2; ++k)
        acc += __int_as_float(__builtin_amdgcn_readlane(__float_as_int(hu), 2 * k)) * Wd[k];
    if (lane == 0) out[b] = sigmoidf_(acc);

#undef TAILT
#undef FULLT
#undef STEPC
#undef LROW
}

// =====================================================================
// FALLBACK: proven R4 fused kernel (unchanged), used if ws too small.
// =====================================================================
__global__ __attribute__((amdgpu_flat_work_group_size(512, 512)))
__attribute__((amdgpu_waves_per_eu(2, 2)))
void fused_kernel(
    const float* __restrict__ x,        // [B*T*S]
    const int*   __restrict__ lengths,  // [B]
    const float* __restrict__ Wi,       // [G1]
    const float* __restrict__ Ui,       // [U1*G1]
    const float* __restrict__ bi,       // [G1]
    const float* __restrict__ Wo,       // [U1*G2]
    const float* __restrict__ Uo,       // [U2*G2]
    const float* __restrict__ bo,       // [G2]
    const float* __restrict__ Wd,       // [U2]
    const float* __restrict__ bd,       // [1]
    float* __restrict__ out)            // [B]
{
    __shared__ __align__(16) _Float16      Pl[T_][G2];      // [t][u*4+g], 48 KB
    __shared__ __align__(16) unsigned short hbb[8][16][40]; // per-wave h tiles
    __shared__ unsigned int flags[NT];
    const int b    = blockIdx.x;
    const int len  = lengths[b];                 // >= 1
    const int tid  = threadIdx.x;
    const int w    = __builtin_amdgcn_readfirstlane(tid >> 6);   // wave 0..7
    const int lane = tid & 63;
    const int q    = lane >> 4;
    const int n    = lane & 15;

    if (tid < NT) flags[tid] = 0;
    __syncthreads();                             // only barrier: flag init

    if (w <= 3) __builtin_amdgcn_s_setprio(2);

    frag_u Bui[8];
#pragma unroll
    for (int tt = 0; tt < 8; ++tt)
#pragma unroll
        for (int k2 = 0; k2 < 4; ++k2)
            Bui[tt].u[k2] = pack2bf(Ui[(8 * q + 2 * k2) * G1 + 16 * tt + n],
                                    Ui[(8 * q + 2 * k2 + 1) * G1 + 16 * tt + n]);
    frag_u Bwo[6];
#pragma unroll
    for (int tt = 0; tt < 6; ++tt)
#pragma unroll
        for (int k2 = 0; k2 < 4; ++k2)
            Bwo[tt].u[k2] = pack2bf(Wo[(8 * q + 2 * k2) * G2 + 16 * tt + n],
                                    Wo[(8 * q + 2 * k2 + 1) * G2 + 16 * tt + n]);
    float bi_l[8], Wi_l[8], bo_l[6];
#pragma unroll
    for (int tt = 0; tt < 8; ++tt) { bi_l[tt] = bi[16 * tt + n]; Wi_l[tt] = Wi[16 * tt + n]; }
#pragma unroll
    for (int tt = 0; tt < 6; ++tt) bo_l[tt] = bo[16 * tt + n];
    int pcol[6];
#pragma unroll
    for (int tt = 0; tt < 6; ++tt) {
        const int col = 16 * tt + n;
        const int g = col / 24;
        pcol[tt] = (col - 24 * g) * 4 + g;
    }

    int tl[3]; int ntl;
    if (w == 0)      { tl[0] = 0; tl[1] = 0;  tl[2] = 0;  ntl = 1; }
    else if (w == 7) { tl[0] = 7; tl[1] = 14; tl[2] = 15; ntl = 3; }
    else             { tl[0] = w; tl[1] = w + 7; tl[2] = 0; ntl = 2; }

#pragma unroll 1
    for (int i = 0; i < ntl; ++i) {
        const int tile = tl[i];
        const int wt0  = tile * 16;
        if (wt0 >= len) break;

        const float* xr = x + (size_t)(b * T_ + wt0 + 4 * q) * S_;
        f32x2 c01[2], c23[2];
#pragma unroll
        for (int uh = 0; uh < 2; ++uh) { c01[uh] = {0.0f, 0.0f}; c23[uh] = {0.0f, 0.0f}; }

        auto activate = [&](f32x4* acc) {
#pragma unroll
            for (int uh = 0; uh < 2; ++uh) {
                const f32x2 zi01 = { acc[0 + uh][0], acc[0 + uh][1] };
                const f32x2 zi23 = { acc[0 + uh][2], acc[0 + uh][3] };
                const f32x2 zf01 = { acc[2 + uh][0], acc[2 + uh][1] };
                const f32x2 zf23 = { acc[2 + uh][2], acc[2 + uh][3] };
                const f32x2 zg01 = { acc[4 + uh][0], acc[4 + uh][1] };
                const f32x2 zg23 = { acc[4 + uh][2], acc[4 + uh][3] };
                const f32x2 zo01 = { acc[6 + uh][0], acc[6 + uh][1] };
                const f32x2 zo23 = { acc[6 + uh][2], acc[6 + uh][3] };

                f32x2 si01, si23, sf01, sf23, rg01, rg23, so01, so23;
                brcp4(dexp2(zi01, KSIG),  dexp2(zi23, KSIG),  si01, si23);
                brcp4(dexp2(zf01, KSIG),  dexp2(zf23, KSIG),  sf01, sf23);
                brcp4(dexp2(zg01, KTANH), dexp2(zg23, KTANH), rg01, rg23);
                brcp4(dexp2(zo01, KSIG),  dexp2(zo23, KSIG),  so01, so23);
                const f32x2 g01 = 1.0f - 2.0f * rg01;
                const f32x2 g23 = 1.0f - 2.0f * rg23;
                c01[uh] = sf01 * c01[uh] + si01 * g01;
                c23[uh] = sf23 * c23[uh] + si23 * g23;
                f32x2 rc01, rc23;
                brcp4(dexp2(c01[uh], KTANH), dexp2(c23[uh], KTANH), rc01, rc23);
                const f32x2 t01 = 1.0f - 2.0f * rc01;
                const f32x2 t23 = 1.0f - 2.0f * rc23;
                const f32x2 h01 = so01 * t01;
                const f32x2 h23 = so23 * t23;
                hbb[w][4 * q + 0][n + 16 * uh] = f2bf(h01.x);
                hbb[w][4 * q + 1][n + 16 * uh] = f2bf(h01.y);
                hbb[w][4 * q + 2][n + 16 * uh] = f2bf(h23.x);
                hbb[w][4 * q + 3][n + 16 * uh] = f2bf(h23.y);
            }
        };

        float xc[4];
#pragma unroll
        for (int r = 0; r < 4; ++r) xc[r] = xr[r * S_];

        {
            const f32x2 xc01 = { xc[0], xc[1] }, xc23 = { xc[2], xc[3] };
            f32x4 acc[8];
#pragma unroll
            for (int tt = 0; tt < 8; ++tt) {
                const f32x2 a01 = xc01 * Wi_l[tt] + bi_l[tt];
                const f32x2 a23 = xc23 * Wi_l[tt] + bi_l[tt];
                acc[tt][0] = a01.x; acc[tt][1] = a01.y;
                acc[tt][2] = a23.x; acc[tt][3] = a23.y;
            }
            activate(acc);
        }
#pragma unroll
        for (int r = 0; r < 4; ++r) xc[r] = xr[r * S_ + 1];

#pragma unroll 1
        for (int s = 1; s < S_; ++s) {
            const int sn = (s + 1 < S_) ? s + 1 : S_ - 1;
            float xnx[4];
#pragma unroll
            for (int r = 0; r < 4; ++r) xnx[r] = xr[r * S_ + sn];

            const f32x2 xc01 = { xc[0], xc[1] }, xc23 = { xc[2], xc[3] };
            f32x4 acc[8];
#pragma unroll
            for (int tt = 0; tt < 8; ++tt) {
                const f32x2 a01 = xc01 * Wi_l[tt] + bi_l[tt];
                const f32x2 a23 = xc23 * Wi_l[tt] + bi_l[tt];
                acc[tt][0] = a01.x; acc[tt][1] = a01.y;
                acc[tt][2] = a23.x; acc[tt][3] = a23.y;
            }

            const short8 A = *(const short8*)&hbb[w][n][8 * q];
#pragma unroll
            for (int tt = 0; tt < 8; ++tt)
                acc[tt] = __builtin_amdgcn_mfma_f32_16x16x32_bf16(A, Bui[tt].v, acc[tt], 0, 0, 0);

            activate(acc);
#pragma unroll
            for (int r = 0; r < 4; ++r) xc[r] = xnx[r];
        }

        {
            const short8 A = *(const short8*)&hbb[w][n][8 * q];
            f32x4 accp[6];
#pragma unroll
            for (int tt = 0; tt < 6; ++tt) {
#pragma unroll
                for (int r = 0; r < 4; ++r) accp[tt][r] = bo_l[tt];
                accp[tt] = __builtin_amdgcn_mfma_f32_16x16x32_bf16(A, Bwo[tt].v, accp[tt], 0, 0, 0);
            }
#pragma unroll
            for (int r = 0; r < 4; ++r) {
                const int tr = wt0 + 4 * q + r;
#pragma unroll
                for (int tt = 0; tt < 6; ++tt)
                    Pl[tr][pcol[tt]] = (_Float16)accp[tt][r];
            }
        }
        __hip_atomic_store(&flags[tile], 1u, __ATOMIC_RELEASE, __HIP_MEMORY_SCOPE_WORKGROUP);
        if (i == 0) {
            if (w == 0) __builtin_amdgcn_s_setprio(3);
            else        __builtin_amdgcn_s_setprio(0);
        }
    }

    if (w != 0) return;

    const int p = lane & 1;
    const int u = (lane < 2 * U2) ? (lane >> 1) : (U2 - 1);
    const int cA = p ? (2 * U2 + u) : u;
    const int cB = p ? (3 * U2 + u) : (U2 + u);

    const float kx = p ? KTANH : KSIG;
    const f32x2 kv  = { kx, KSIG };
    const f32x2 mAB = { p ? (-2.0f * KTANH) : 1.0f, 1.0f };
    const f32x2 aAB = { p ? KTANH : 0.0f, 0.0f };

    f32x2 w2_[U2];
#pragma unroll
    for (int k = 0; k < U2; ++k) {
        w2_[k].x = Uo[k * G2 + cA] * kx;
        w2_[k].y = Uo[k * G2 + cB] * KSIG;
    }

    auto cvt2 = [&](unsigned rw) -> f32x2 {
        h2x s_; s_.u32 = rw;
        f32x2 r; r.x = (float)s_.h[0]; r.y = (float)s_.h[1];
        return r * kv;
    };

    const int rowoff = 8 * u + 4 * p;
    const char* Pb = reinterpret_cast<const char*>(&Pl[0][0]);
    const int ntiles = (len + 15) >> 4;

    unsigned bufA[16], bufB[16];

    float cs = 0.0f, hu = 0.0f;

#define STEP_ROW(RW) do {                                                     \
    const f32x2 pr = cvt2(RW);                                                \
    float hk[U2];                                                             \
    _Pragma("unroll")                                                         \
    for (int kq = 0; kq < U2; ++kq)                                           \
        hk[kq] = __int_as_float(                                              \
            __builtin_amdgcn_readlane(__float_as_int(hu), 2 * kq));           \
    f32x2 ab0 = pr;                                                           \
    f32x2 ab1 = {0.f,0.f}, ab2 = {0.f,0.f}, ab3 = {0.f,0.f};                  \
    f32x2 ab4 = {0.f,0.f}, ab5 = {0.f,0.f}, ab6 = {0.f,0.f}, ab7 = {0.f,0.f}; \
    _Pragma("unroll")                                                         \
    for (int mq = 0; mq < 3; ++mq) {                                          \
        ab0 += w2_[8 * mq + 0] * hk[8 * mq + 0];                              \
        ab1 += w2_[8 * mq + 1] * hk[8 * mq + 1];                              \
        ab2 += w2_[8 * mq + 2] * hk[8 * mq + 2];                              \
        ab3 += w2_[8 * mq + 3] * hk[8 * mq + 3];                              \
        ab4 += w2_[8 * mq + 4] * hk[8 * mq + 4];                              \
        ab5 += w2_[8 * mq + 5] * hk[8 * mq + 5];                              \
        ab6 += w2_[8 * mq + 6] * hk[8 * mq + 6];                              \
        ab7 += w2_[8 * mq + 7] * hk[8 * mq + 7];                              \
    }                                                                         \
    const f32x2 zz = (((ab0 + ab1) + (ab2 + ab3)) +                           \
                      ((ab4 + ab5) + (ab6 + ab7)));                           \
    f32x2 e_;                                                                 \
    e_.x = __builtin_amdgcn_exp2f(zz.x);                                      \
    e_.y = __builtin_amdgcn_exp2f(zz.y);                                      \
    const f32x2 d_ = e_ + 1.0f;                                               \
    f32x2 r_;                                                                 \
    r_.x = __builtin_amdgcn_rcpf(d_.x);                                       \
    r_.y = __builtin_amdgcn_rcpf(d_.y);                                       \
    const f32x2 o2 = r_ * mAB + aAB;                                          \
    const float swx = dpp_xor1(o2.x);                                         \
    const float swy = dpp_xor1(o2.y);                                         \
    cs = o2.y * cs + o2.x * swx;                                              \
    const float e2 = __builtin_amdgcn_exp2f(cs);                              \
    const float r2 = __builtin_amdgcn_rcpf(1.0f + e2);                        \
    const float tc = 1.0f - 2.0f * r2;                                        \
    hu = swy * tc;                                                            \
} while (0)

#define TILE_BODY(K, CUR, NXT, J0) do {                                       \
    _Pragma("unroll")                                                         \
    for (int j = (J0); j < 8; ++j) {                                          \
        if (16 * (K) + j >= len) goto p2done;                                 \
        STEP_ROW(CUR[j]);                                                     \
    }                                                                         \
    if ((K) + 1 < ntiles) {                                                   \
        while (__hip_atomic_load(&flags[(K) + 1], __ATOMIC_ACQUIRE,           \
                                 __HIP_MEMORY_SCOPE_WORKGROUP) == 0u)         \
            __builtin_amdgcn_s_sleep(1);                                      \
        _Pragma("unroll")                                                     \
        for (int j = 0; j < 16; ++j)                                          \
            NXT[j] = *reinterpret_cast<const unsigned*>(                      \
                Pb + (16 * ((K) + 1) + j) * (G2 * 2) + rowoff);               \
    }                                                                         \
    _Pragma("unroll")                                                         \
    for (int j = 8; j < 16; ++j) {                                            \
        if (16 * (K) + j >= len) goto p2done;                                 \
        STEP_ROW(CUR[j]);                                                     \
    }                                                                         \
} while (0)

#pragma unroll
    for (int j = 0; j < 16; ++j)
        bufA[j] = *reinterpret_cast<const unsigned*>(Pb + j * (G2 * 2) + rowoff);

    {
        const f32x2 z0 = cvt2(bufA[0]);
        f32x2 e_;
        e_.x = __builtin_amdgcn_exp2f(z0.x);
        e_.y = __builtin_amdgcn_exp2f(z0.y);
        const f32x2 d_ = e_ + 1.0f;
        f32x2 r_;
        r_.x = __builtin_amdgcn_rcpf(d_.x);
        r_.y = __builtin_amdgcn_rcpf(d_.y);
        const f32x2 o2 = r_ * mAB + aAB;
        const float swx = dpp_xor1(o2.x);
        const float swy = dpp_xor1(o2.y);
        cs = o2.x * swx;
        const float e2 = __builtin_amdgcn_exp2f(cs);
        const float r2 = __builtin_amdgcn_rcpf(1.0f + e2);
        const float tc = 1.0f - 2.0f * r2;
        hu = swy * tc;
    }

    TILE_BODY(0, bufA, bufB, 1);
#pragma unroll 1
    for (int k = 1; k < ntiles; ++k) {
        if (k & 1) TILE_BODY(k, bufB, bufA, 0);
        else       TILE_BODY(k, bufA, bufB, 0);
    }
p2done: ;

    float acc = bd[0];
#pragma unroll
    for (int k = 0; k < U2; ++k)
        acc += __int_as_float(__builtin_amdgcn_readlane(__float_as_int(hu), 2 * k)) * Wd[k];
    if (lane == 0) out[b] = sigmoidf_(acc);

#undef TILE_BODY
#undef STEP_ROW
}

extern "C" void kernel_launch(void* const* d_in, const int* in_sizes, int n_in,
                              void* d_out, int out_size, void* d_ws, size_t ws_size,
                              hipStream_t stream) {
    const float* x       = (const float*)d_in[0];
    const int*   lengths = (const int*)  d_in[1];
    const float* Wi      = (const float*)d_in[2];
    const float* Ui      = (const float*)d_in[3];
    const float* bi      = (const float*)d_in[4];
    const float* Wo      = (const float*)d_in[5];
    const float* Uo      = (const float*)d_in[6];
    const float* bo      = (const float*)d_in[7];
    const float* Wd      = (const float*)d_in[8];
    const float* bd      = (const float*)d_in[9];
    float* out = (float*)d_out;

    const size_t pbytes = (size_t)B_ * T_ * G2 * sizeof(_Float16);  // 12.6 MB
    if (d_ws != nullptr && ws_size >= pbytes) {
        _Float16* gP = (_Float16*)d_ws;
        prod_kernel<<<dim3(B_ * NT), dim3(64), 0, stream>>>(
            x, lengths, Wi, Ui, bi, Wo, bo, gP);
        cons_kernel<<<dim3(B_), dim3(64), 0, stream>>>(
            lengths, Uo, Wd, bd, gP, out);
    } else {
        fused_kernel<<<dim3(B_), dim3(512), 0, stream>>>(
            x, lengths, Wi, Ui, bi, Wo, Uo, bo, Wd, bd, out);
    }
}

// Round 6
// 141.557 us; speedup vs baseline: 1.2530x; 1.2530x over previous
//
#include <hip/hip_runtime.h>

#define B_  256
#define T_  256
#define S_  20
#define U1  32
#define G1  128   // 4*U1
#define U2  24
#define G2  96    // 4*U2
#define NT  16    // 16-row t-tiles per sequence

typedef __attribute__((ext_vector_type(8))) short short8;   // 8 bf16 = 4 VGPRs
typedef __attribute__((ext_vector_type(4))) float f32x4;    // MFMA acc
typedef __attribute__((ext_vector_type(2))) float f32x2;    // pk pair

#define KSIG  (-1.44269504f)   // -log2(e)
#define KTANH ( 2.88539008f)   // 2*log2(e)

// Raw-HW activations (v_exp_f32 = 2^x, pre-scaled by log2e). R7: 134->74us.
__device__ __forceinline__ float sigmoidf_(float x) {
    return __builtin_amdgcn_rcpf(1.0f + __builtin_amdgcn_exp2f(x * KSIG));
}
// quad_perm [1,0,3,2]: lane ^= 1 swap, pure-VALU
__device__ __forceinline__ float dpp_xor1(float x) {
    return __int_as_float(__builtin_amdgcn_update_dpp(
        0, __float_as_int(x), 0xB1, 0xF, 0xF, true));
}
// d = 1 + exp2(k*z), componentwise exp2 (trans is scalar-only; mul/add pack)
__device__ __forceinline__ f32x2 dexp2(f32x2 z, float k) {
    f32x2 t = z * k;
    f32x2 e;
    e.x = __builtin_amdgcn_exp2f(t.x);
    e.y = __builtin_amdgcn_exp2f(t.y);
    return e + 1.0f;
}
// elementwise recip of 4 independent denoms with 2 rcp + 3 pk_mul (vs 4 rcp)
__device__ __forceinline__ void brcp4(f32x2 d01, f32x2 d23, f32x2& s01, f32x2& s23) {
    const f32x2 m = d01 * d23;
    f32x2 R;
    R.x = __builtin_amdgcn_rcpf(m.x);
    R.y = __builtin_amdgcn_rcpf(m.y);
    s01 = R * d23;
    s23 = R * d01;
}

__device__ __forceinline__ unsigned short f2bf(float a) {
    unsigned int u = __float_as_uint(a);
    u += 0x7FFFu + ((u >> 16) & 1u);
    return (unsigned short)(u >> 16);
}
__device__ __forceinline__ unsigned int pack2bf(float a, float b) {
    unsigned int ua = __float_as_uint(a); ua += 0x7FFFu + ((ua >> 16) & 1u);
    unsigned int ub = __float_as_uint(b); ub += 0x7FFFu + ((ub >> 16) & 1u);
    return (ua >> 16) | (ub & 0xFFFF0000u);
}
union frag_u { short8 v; unsigned int u[4]; };
union h2x  { unsigned int u32; _Float16 h[2]; };

// FUSED producer-consumer kernel: 1 block/sequence, 512 threads (8 waves).
// R18 (post-split-revert): R5 taught (a) per-tile producer latency ~12us
// (issue-serial), (b) pure consumer compute ~40us (split cons_kernel,
// verified) => fused-R4's 80.7us carried ~35us of producer-gating + SIMD
// contention. Changes vs R4:
//  * wave 4 (consumer's SIMD-mate under w%4 wave->SIMD round-robin)
//    produces NOTHING -> consumer owns its SIMD after startup. 15 tiles
//    over 6 producers: w1{1,7,13} w2{2,8,14} w3{3,9,15} w5{4,10} w6{5,11}
//    w7{6,12} -- early-needed tiles still land first.
//  * consumer body = R5's verified cons structure: guard-free full tiles
//    + tail, fma-merged hu; flag spin at tile START (16 steps of slack).
__global__ __attribute__((amdgpu_flat_work_group_size(512, 512)))
__attribute__((amdgpu_waves_per_eu(2, 2)))
void fused_kernel(
    const float* __restrict__ x,        // [B*T*S]
    const int*   __restrict__ lengths,  // [B]
    const float* __restrict__ Wi,       // [G1]
    const float* __restrict__ Ui,       // [U1*G1]
    const float* __restrict__ bi,       // [G1]
    const float* __restrict__ Wo,       // [U1*G2]
    const float* __restrict__ Uo,       // [U2*G2]
    const float* __restrict__ bo,       // [G2]
    const float* __restrict__ Wd,       // [U2]
    const float* __restrict__ bd,       // [1]
    float* __restrict__ out)            // [B]
{
    __shared__ __align__(16) _Float16      Pl[T_][G2];      // [t][u*4+g], 48 KB
    __shared__ __align__(16) unsigned short hbb[8][16][40]; // per-wave h tiles
    __shared__ unsigned int flags[NT];
    const int b    = blockIdx.x;
    const int len  = lengths[b];                 // >= 1
    const int tid  = threadIdx.x;
    const int w    = __builtin_amdgcn_readfirstlane(tid >> 6);   // wave 0..7
    const int lane = tid & 63;
    const int q    = lane >> 4;
    const int n    = lane & 15;

    if (tid < NT) flags[tid] = 0;
    __syncthreads();                             // only barrier: flag init

    // all first-round producers (and the consumer making tile 0) at prio 2
    if (w != 4) __builtin_amdgcn_s_setprio(2);

    // ---- one-time fragment/bias loads ----
    frag_u Bui[8];
#pragma unroll
    for (int tt = 0; tt < 8; ++tt)
#pragma unroll
        for (int k2 = 0; k2 < 4; ++k2)
            Bui[tt].u[k2] = pack2bf(Ui[(8 * q + 2 * k2) * G1 + 16 * tt + n],
                                    Ui[(8 * q + 2 * k2 + 1) * G1 + 16 * tt + n]);
    frag_u Bwo[6];
#pragma unroll
    for (int tt = 0; tt < 6; ++tt)
#pragma unroll
        for (int k2 = 0; k2 < 4; ++k2)
            Bwo[tt].u[k2] = pack2bf(Wo[(8 * q + 2 * k2) * G2 + 16 * tt + n],
                                    Wo[(8 * q + 2 * k2 + 1) * G2 + 16 * tt + n]);
    float bi_l[8], Wi_l[8], bo_l[6];
#pragma unroll
    for (int tt = 0; tt < 8; ++tt) { bi_l[tt] = bi[16 * tt + n]; Wi_l[tt] = Wi[16 * tt + n]; }
#pragma unroll
    for (int tt = 0; tt < 6; ++tt) bo_l[tt] = bo[16 * tt + n];
    // P-store targets: col=16tt+n -> (g=col/24, u=col%24) -> offset u*4+g
    int pcol[6];
#pragma unroll
    for (int tt = 0; tt < 6; ++tt) {
        const int col = 16 * tt + n;
        const int g = col / 24;
        pcol[tt] = (col - 24 * g) * 4 + g;
    }

    // ---- tile worklists: w0:{0}; w4: none (consumer's SIMD-mate);
    //      w1-3: {w, w+6, w+12}; w5-7: {w-1, w+5}. Covers 0..15 once.
    int tl[3]; int ntl;
    if (w == 0)      { tl[0] = 0;     tl[1] = 0;     tl[2] = 0;      ntl = 1; }
    else if (w == 4) { tl[0] = 0;     tl[1] = 0;     tl[2] = 0;      ntl = 0; }
    else if (w <= 3) { tl[0] = w;     tl[1] = w + 6; tl[2] = w + 12; ntl = 3; }
    else             { tl[0] = w - 1; tl[1] = w + 5; tl[2] = 0;      ntl = 2; }

#pragma unroll 1
    for (int i = 0; i < ntl; ++i) {
        const int tile = tl[i];
        const int wt0  = tile * 16;
        if (wt0 >= len) break;                   // lists increasing: later also masked

        const float* xr = x + (size_t)(b * T_ + wt0 + 4 * q) * S_;
        f32x2 c01[2], c23[2];
#pragma unroll
        for (int uh = 0; uh < 2; ++uh) { c01[uh] = {0.0f, 0.0f}; c23[uh] = {0.0f, 0.0f}; }

        // packed activation block: 60 trans ops/step, pk elsewhere
        auto activate = [&](f32x4* acc) {
#pragma unroll
            for (int uh = 0; uh < 2; ++uh) {
                const f32x2 zi01 = { acc[0 + uh][0], acc[0 + uh][1] };
                const f32x2 zi23 = { acc[0 + uh][2], acc[0 + uh][3] };
                const f32x2 zf01 = { acc[2 + uh][0], acc[2 + uh][1] };
                const f32x2 zf23 = { acc[2 + uh][2], acc[2 + uh][3] };
                const f32x2 zg01 = { acc[4 + uh][0], acc[4 + uh][1] };
                const f32x2 zg23 = { acc[4 + uh][2], acc[4 + uh][3] };
                const f32x2 zo01 = { acc[6 + uh][0], acc[6 + uh][1] };
                const f32x2 zo23 = { acc[6 + uh][2], acc[6 + uh][3] };

                f32x2 si01, si23, sf01, sf23, rg01, rg23, so01, so23;
                brcp4(dexp2(zi01, KSIG),  dexp2(zi23, KSIG),  si01, si23);
                brcp4(dexp2(zf01, KSIG),  dexp2(zf23, KSIG),  sf01, sf23);
                brcp4(dexp2(zg01, KTANH), dexp2(zg23, KTANH), rg01, rg23);
                brcp4(dexp2(zo01, KSIG),  dexp2(zo23, KSIG),  so01, so23);
                const f32x2 g01 = 1.0f - 2.0f * rg01;
                const f32x2 g23 = 1.0f - 2.0f * rg23;
                c01[uh] = sf01 * c01[uh] + si01 * g01;
                c23[uh] = sf23 * c23[uh] + si23 * g23;
                f32x2 rc01, rc23;
                brcp4(dexp2(c01[uh], KTANH), dexp2(c23[uh], KTANH), rc01, rc23);
                const f32x2 t01 = 1.0f - 2.0f * rc01;
                const f32x2 t23 = 1.0f - 2.0f * rc23;
                const f32x2 h01 = so01 * t01;
                const f32x2 h23 = so23 * t23;
                hbb[w][4 * q + 0][n + 16 * uh] = f2bf(h01.x);
                hbb[w][4 * q + 1][n + 16 * uh] = f2bf(h01.y);
                hbb[w][4 * q + 2][n + 16 * uh] = f2bf(h23.x);
                hbb[w][4 * q + 3][n + 16 * uh] = f2bf(h23.y);
            }
        };

        float xc[4];
#pragma unroll
        for (int r = 0; r < 4; ++r) xc[r] = xr[r * S_];

        // peeled s = 0 (h == 0: no MFMA)
        {
            const f32x2 xc01 = { xc[0], xc[1] }, xc23 = { xc[2], xc[3] };
            f32x4 acc[8];
#pragma unroll
            for (int tt = 0; tt < 8; ++tt) {
                const f32x2 a01 = xc01 * Wi_l[tt] + bi_l[tt];
                const f32x2 a23 = xc23 * Wi_l[tt] + bi_l[tt];
                acc[tt][0] = a01.x; acc[tt][1] = a01.y;
                acc[tt][2] = a23.x; acc[tt][3] = a23.y;
            }
            activate(acc);
        }
#pragma unroll
        for (int r = 0; r < 4; ++r) xc[r] = xr[r * S_ + 1];

        // steady state s = 1..19
#pragma unroll 1
        for (int s = 1; s < S_; ++s) {
            const int sn = (s + 1 < S_) ? s + 1 : S_ - 1;
            float xnx[4];
#pragma unroll
            for (int r = 0; r < 4; ++r) xnx[r] = xr[r * S_ + sn];

            const f32x2 xc01 = { xc[0], xc[1] }, xc23 = { xc[2], xc[3] };
            f32x4 acc[8];
#pragma unroll
            for (int tt = 0; tt < 8; ++tt) {
                const f32x2 a01 = xc01 * Wi_l[tt] + bi_l[tt];
                const f32x2 a23 = xc23 * Wi_l[tt] + bi_l[tt];
                acc[tt][0] = a01.x; acc[tt][1] = a01.y;
                acc[tt][2] = a23.x; acc[tt][3] = a23.y;
            }

            const short8 A = *(const short8*)&hbb[w][n][8 * q];
#pragma unroll
            for (int tt = 0; tt < 8; ++tt)
                acc[tt] = __builtin_amdgcn_mfma_f32_16x16x32_bf16(A, Bui[tt].v, acc[tt], 0, 0, 0);

            activate(acc);
#pragma unroll
            for (int r = 0; r < 4; ++r) xc[r] = xnx[r];
        }

        // P tile = bo + h @ Wo -> LDS, unit-major pair layout
        {
            const short8 A = *(const short8*)&hbb[w][n][8 * q];
            f32x4 accp[6];
#pragma unroll
            for (int tt = 0; tt < 6; ++tt) {
#pragma unroll
                for (int r = 0; r < 4; ++r) accp[tt][r] = bo_l[tt];
                accp[tt] = __builtin_amdgcn_mfma_f32_16x16x32_bf16(A, Bwo[tt].v, accp[tt], 0, 0, 0);
            }
#pragma unroll
            for (int r = 0; r < 4; ++r) {
                const int tr = wt0 + 4 * q + r;
#pragma unroll
                for (int tt = 0; tt < 6; ++tt)
                    Pl[tr][pcol[tt]] = (_Float16)accp[tt][r];
            }
        }
        // release this tile to the consumer (DS ops in-order; release fences)
        __hip_atomic_store(&flags[tile], 1u, __ATOMIC_RELEASE, __HIP_MEMORY_SCOPE_WORKGROUP);
        if (i == 0) {
            if (w == 0) __builtin_amdgcn_s_setprio(3);   // consumer priority
            else        __builtin_amdgcn_s_setprio(0);   // back to baseline
        }
    }

    if (w != 0) return;                          // producers retire

    // ================= phase 2: outer LSTM + head (wave 0) =================
    // Parity pipeline (R4/R5-verified): even lane 2u holds (z_i,z_f)
    // prescaled KSIG; odd (z_g,z_o) prescaled (KTANH,KSIG). cs = KTANH*c and
    // hu live on EVEN lanes. Guard-free full tiles + tail; fma-merged hu.
    const int p = lane & 1;
    const int u = (lane < 2 * U2) ? (lane >> 1) : (U2 - 1);
    const int cA = p ? (2 * U2 + u) : u;
    const int cB = p ? (3 * U2 + u) : (U2 + u);

    const float kx = p ? KTANH : KSIG;
    const f32x2 kv  = { kx, KSIG };
    const f32x2 mAB = { p ? (-2.0f * KTANH) : 1.0f, 1.0f };
    const f32x2 aAB = { p ? KTANH : 0.0f, 0.0f };

    f32x2 w2_[U2];                               // prescaled weight pairs
#pragma unroll
    for (int k = 0; k < U2; ++k) {
        w2_[k].x = Uo[k * G2 + cA] * kx;
        w2_[k].y = Uo[k * G2 + cB] * KSIG;
    }

    const int rowoff = 8 * u + 4 * p;            // bytes; row stride 192 B
    const char* Pb = reinterpret_cast<const char*>(&Pl[0][0]);
    const int nfull  = len >> 4;
    const int rem    = len & 15;
    const int ntiles = (len + 15) >> 4;

    unsigned bufA[16], bufB[16];                 // double-buffered row regs
    float cs = 0.0f, hu = 0.0f;

#define LROW(T) (*reinterpret_cast<const unsigned*>(Pb + (T) * (G2 * 2) + rowoff))

// one recurrence step; hu fma-merged: hu = fma(-2*swy, r2, swy)  [R5-verified]
#define STEPC(RW) do {                                                        \
    h2x s_; s_.u32 = (RW);                                                    \
    f32x2 pr; pr.x = (float)s_.h[0]; pr.y = (float)s_.h[1]; pr *= kv;         \
    float hk[U2];                                                             \
    _Pragma("unroll")                                                         \
    for (int kq = 0; kq < U2; ++kq)                                           \
        hk[kq] = __int_as_float(                                              \
            __builtin_amdgcn_readlane(__float_as_int(hu), 2 * kq));           \
    f32x2 ab0 = pr;                                                           \
    f32x2 ab1 = {0.f,0.f}, ab2 = {0.f,0.f}, ab3 = {0.f,0.f};                  \
    f32x2 ab4 = {0.f,0.f}, ab5 = {0.f,0.f}, ab6 = {0.f,0.f}, ab7 = {0.f,0.f}; \
    _Pragma("unroll")                                                         \
    for (int mq = 0; mq < 3; ++mq) {                                          \
        ab0 += w2_[8 * mq + 0] * hk[8 * mq + 0];                              \
        ab1 += w2_[8 * mq + 1] * hk[8 * mq + 1];                              \
        ab2 += w2_[8 * mq + 2] * hk[8 * mq + 2];                              \
        ab3 += w2_[8 * mq + 3] * hk[8 * mq + 3];                              \
        ab4 += w2_[8 * mq + 4] * hk[8 * mq + 4];                              \
        ab5 += w2_[8 * mq + 5] * hk[8 * mq + 5];                              \
        ab6 += w2_[8 * mq + 6] * hk[8 * mq + 6];                              \
        ab7 += w2_[8 * mq + 7] * hk[8 * mq + 7];                              \
    }                                                                         \
    const f32x2 zz = (((ab0 + ab1) + (ab2 + ab3)) +                           \
                      ((ab4 + ab5) + (ab6 + ab7)));                           \
    f32x2 e_;                                                                 \
    e_.x = __builtin_amdgcn_exp2f(zz.x);                                      \
    e_.y = __builtin_amdgcn_exp2f(zz.y);                                      \
    const f32x2 d_ = e_ + 1.0f;                                               \
    f32x2 r_;                                                                 \
    r_.x = __builtin_amdgcn_rcpf(d_.x);                                       \
    r_.y = __builtin_amdgcn_rcpf(d_.y);                                       \
    const f32x2 o2 = r_ * mAB + aAB;                                          \
    const float swx  = dpp_xor1(o2.x);                                        \
    const float swy  = dpp_xor1(o2.y);                                        \
    const float swy2 = -2.0f * swy;          /* exact; off the cs-chain */    \
    cs = o2.y * cs + o2.x * swx;                                              \
    const float e2 = __builtin_amdgcn_exp2f(cs);                              \
    const float r2 = __builtin_amdgcn_rcpf(1.0f + e2);                        \
    hu = swy2 * r2 + swy;                                                     \
} while (0)

// full 16-step tile, NO per-step guards. Spin + prefetch of tile K+1 at
// the TOP: 16 steps of slack before its first use (lgkmcnt at next tile).
#define FULLT(K, CUR, NXT, J0) do {                                           \
    if ((K) + 1 < ntiles) {                                                   \
        while (__hip_atomic_load(&flags[(K) + 1], __ATOMIC_ACQUIRE,           \
                                 __HIP_MEMORY_SCOPE_WORKGROUP) == 0u)         \
            __builtin_amdgcn_s_sleep(1);                                      \
        _Pragma("unroll")                                                     \
        for (int j = 0; j < 16; ++j) NXT[j] = LROW(16 * ((K) + 1) + j);       \
    }                                                                         \
    _Pragma("unroll")                                                         \
    for (int j = (J0); j < 16; ++j) STEPC(CUR[j]);                            \
} while (0)

#define TAILT(CUR, J0) do {                                                   \
    _Pragma("unroll")                                                         \
    for (int j = (J0); j < 16; ++j) {                                         \
        if (j >= rem) break;                                                  \
        STEPC(CUR[j]);                                                        \
    }                                                                         \
} while (0)

    // tile 0: produced by this wave itself (own DS writes are in-order)
#pragma unroll
    for (int j = 0; j < 16; ++j) bufA[j] = LROW(j);

    {   // peeled t = 0 (h == 0, c == 0)
        h2x s_; s_.u32 = bufA[0];
        f32x2 z0; z0.x = (float)s_.h[0]; z0.y = (float)s_.h[1]; z0 *= kv;
        f32x2 e_;
        e_.x = __builtin_amdgcn_exp2f(z0.x);
        e_.y = __builtin_amdgcn_exp2f(z0.y);
        const f32x2 d_ = e_ + 1.0f;
        f32x2 r_;
        r_.x = __builtin_amdgcn_rcpf(d_.x);
        r_.y = __builtin_amdgcn_rcpf(d_.y);
        const f32x2 o2 = r_ * mAB + aAB;
        const float swx = dpp_xor1(o2.x);
        const float swy = dpp_xor1(o2.y);
        cs = o2.x * swx;                         // c_prev = 0
        const float e2 = __builtin_amdgcn_exp2f(cs);
        const float r2 = __builtin_amdgcn_rcpf(1.0f + e2);
        hu = (-2.0f * swy) * r2 + swy;
    }

    if (nfull == 0) {
        TAILT(bufA, 1);                          // len < 16
    } else {
        FULLT(0, bufA, bufB, 1);
#pragma unroll 1
        for (int k = 1; k < nfull; ++k) {
            if (k & 1) FULLT(k, bufB, bufA, 0);
            else       FULLT(k, bufA, bufB, 0);
        }
        if (rem) {
            if (nfull & 1) TAILT(bufB, 0);
            else           TAILT(bufA, 0);
        }
    }

    // dense sigmoid head (h on even lanes)
    float acc = bd[0];
#pragma unroll
    for (int k = 0; k < U2; ++k)
        acc += __int_as_float(__builtin_amdgcn_readlane(__float_as_int(hu), 2 * k)) * Wd[k];
    if (lane == 0) out[b] = sigmoidf_(acc);

#undef TAILT
#undef FULLT
#undef STEPC
#undef LROW
}

extern "C" void kernel_launch(void* const* d_in, const int* in_sizes, int n_in,
                              void* d_out, int out_size, void* d_ws, size_t ws_size,
                              hipStream_t stream) {
    const float* x       = (const float*)d_in[0];
    const int*   lengths = (const int*)  d_in[1];
    const float* Wi      = (const float*)d_in[2];
    const float* Ui      = (const float*)d_in[3];
    const float* bi      = (const float*)d_in[4];
    const float* Wo      = (const float*)d_in[5];
    const float* Uo      = (const float*)d_in[6];
    const float* bo      = (const float*)d_in[7];
    const float* Wd      = (const float*)d_in[8];
    const float* bd      = (const float*)d_in[9];
    float* out = (float*)d_out;

    fused_kernel<<<dim3(B_), dim3(512), 0, stream>>>(
        x, lengths, Wi, Ui, bi, Wo, Uo, bo, Wd, bd, out);
}